// Round 12
// baseline (224.758 us; speedup 1.0000x reference)
//
#include <hip/hip_runtime.h>
#include <cstdint>

#define D 256
#define NC 32
#define NCLS 10
#define KNN 10
#define KROWS 128

typedef float f32x16 __attribute__((ext_vector_type(16)));
typedef short short8v __attribute__((ext_vector_type(8)));
typedef const __attribute__((address_space(1))) unsigned int* gp1_t;
typedef __attribute__((address_space(3))) unsigned int* sp3_t;

__device__ __forceinline__ float wave_sum(float v) {
  #pragma unroll
  for (int off = 32; off; off >>= 1) v += __shfl_xor(v, off);
  return v;
}

__device__ __forceinline__ uint32_t fbits(float x) { return __builtin_bit_cast(uint32_t, x); }
__device__ __forceinline__ float bcast(uint32_t b) { return __builtin_bit_cast(float, b); }

// ============ k_key: dist-key + block-top10, barrier-free wave pipeline ============
// 128 rows/block, 4 waves; wave w owns rows w*32..+31 (private 4KB LDS dbuf).
// 16 K-steps of 16: stage next chunk (2x global_load_lds), s_waitcnt vmcnt(2)
// (counted, never 0 mid-loop; wave-private => no cross-wave hazard), ds_read x-frag
// + C-frag (block-shared, read-only), bf16 hi/lo split, 3 MFMA.
// Epilogue: keys -> wave LDS region (x2 added via shfl), ONE barrier, 8-lane teams
// select per-concept block-top-10 (exact, lex (v,idx)) -> candK/candI [c][blk][10].
__global__ __launch_bounds__(256, 3) void k_key(const float* __restrict__ X,
                                                const uint4* __restrict__ Chi,
                                                const uint4* __restrict__ Clo,
                                                float* __restrict__ candK,
                                                int* __restrict__ candI,
                                                int N, int G) {
  __shared__ float4 xt[4][256];    // 16 KB: per wave 2 bufs x 32 rows x 4 f4
  __shared__ uint4 cfh[1024];      // 16 KB: Chi frags [ks*64 + lane]
  __shared__ uint4 cfl[1024];      // 16 KB: Clo frags
  int t = threadIdx.x;
  int lane = t & 63;
  int wvu = __builtin_amdgcn_readfirstlane(t >> 6);   // 0..3
  int r32 = lane & 31, g = lane >> 5;
  int rowbase = blockIdx.x * KROWS;

  // --- stage C fragments (32 KB) once; wave w copies its quarter of each ---
  // global source is PER-LANE (base + lane); LDS dest = uniform base + lane*16B.
  #pragma unroll
  for (int i = 0; i < 4; ++i) {
    const uint4* srcH = Chi + wvu * 256 + i * 64 + lane;
    __builtin_amdgcn_global_load_lds((gp1_t)(const void*)srcH,
        (sp3_t)(void*)(&cfh[wvu * 256 + i * 64]), 16, 0, 0);
    const uint4* srcL = Clo + wvu * 256 + i * 64 + lane;
    __builtin_amdgcn_global_load_lds((gp1_t)(const void*)srcL,
        (sp3_t)(void*)(&cfl[wvu * 256 + i * 64]), 16, 0, 0);
  }
  __syncthreads();   // drains vmcnt+lgkmcnt; cfh/cfl visible to all waves

  // wave-private X stage: chunk ks = 16 floats/row; 32 rows = 128 f4 = 2 instrs
  auto stage = [&](int buf, int ks) {
    #pragma unroll
    for (int i = 0; i < 2; ++i) {
      int s = i * 64 + lane;                 // linear f4 slot in wave buf
      int r = s >> 2, m = s & 3;
      int f4 = m ^ (r & 3);                  // inverse swizzle on SOURCE
      int gr = rowbase + wvu * 32 + r; if (gr >= N) gr = N - 1;
      const float* src = X + (size_t)gr * D + ks * 16 + f4 * 4;
      __builtin_amdgcn_global_load_lds((gp1_t)(const void*)src,
          (sp3_t)(void*)(&xt[wvu][buf * 128 + i * 64]), 16, 0, 0);
    }
  };

  stage(0, 0);

  f32x16 a0, a1, a2;
  #pragma unroll
  for (int i = 0; i < 16; ++i) { a0[i] = 0.f; a1[i] = 0.f; a2[i] = 0.f; }
  float x2 = 0.f;
  int sw3 = r32 & 3;

  for (int ks = 0; ks < 16; ++ks) {
    int cb = ks & 1;
    if (ks < 15) {
      stage(cb ^ 1, ks + 1);
      asm volatile("s_waitcnt vmcnt(2)" ::: "memory");   // current chunk landed
    } else {
      asm volatile("s_waitcnt vmcnt(0)" ::: "memory");
    }
    __builtin_amdgcn_sched_barrier(0);
    // x-fragment: lane (r32,g) needs floats g*8..g*8+7 = logical slots g*2, g*2+1
    float4 xa = xt[wvu][cb * 128 + r32 * 4 + ((g * 2) ^ sw3)];
    float4 xb = xt[wvu][cb * 128 + r32 * 4 + ((g * 2 + 1) ^ sw3)];
    float xs[8] = {xa.x, xa.y, xa.z, xa.w, xb.x, xb.y, xb.z, xb.w};
    uint32_t hp[4], lp[4];
    #pragma unroll
    for (int p = 0; p < 4; ++p) {
      float x0 = xs[2 * p], x1 = xs[2 * p + 1];
      x2 = fmaf(x0, x0, x2); x2 = fmaf(x1, x1, x2);
      uint32_t h0 = fbits(x0) & 0xFFFF0000u, h1 = fbits(x1) & 0xFFFF0000u;
      hp[p] = h1 | (h0 >> 16);
      float r0 = x0 - bcast(h0), r1 = x1 - bcast(h1);
      lp[p] = (fbits(r1) & 0xFFFF0000u) | (fbits(r0) >> 16);
    }
    short8v xh = __builtin_bit_cast(short8v, make_uint4(hp[0], hp[1], hp[2], hp[3]));
    short8v xl = __builtin_bit_cast(short8v, make_uint4(lp[0], lp[1], lp[2], lp[3]));
    short8v bh = __builtin_bit_cast(short8v, cfh[ks * 64 + lane]);
    short8v bl = __builtin_bit_cast(short8v, cfl[ks * 64 + lane]);
    a0 = __builtin_amdgcn_mfma_f32_32x32x16_bf16(xh, bh, a0, 0, 0, 0);
    a1 = __builtin_amdgcn_mfma_f32_32x32x16_bf16(xh, bl, a1, 0, 0, 0);
    a2 = __builtin_amdgcn_mfma_f32_32x32x16_bf16(xl, bh, a2, 0, 0, 0);
  }

  x2 += __shfl_xor(x2, 32);          // full |x|^2 of row r32 (both k-halves)

  // --- epilogue: keys into wave's own (now idle) X region: kl[Xrow*32 + concept] ---
  float* klw = reinterpret_cast<float*>(&xt[wvu][0]);
  #pragma unroll
  for (int i = 0; i < 16; ++i) {
    int rr = (i & 3) + 8 * (i >> 2) + 4 * g;        // X-row within 32-tile
    float x2r = __shfl(x2, rr);                      // x2 of row rr
    klw[rr * 32 + r32] = fmaf(-2.f, a0[i] + a1[i] + a2[i], x2r);  // r32 = concept
  }
  __syncthreads();   // all waves' keys visible

  // --- block top-10 per concept: team = 8 lanes (aligned), c = t>>3, sub = t&7 ---
  {
    int c = t >> 3, sub = t & 7;
    const float INF = 3.4e38f;
    float bk[KNN]; int bi[KNN];
    #pragma unroll
    for (int q = 0; q < KNN; ++q) { bk[q] = INF; bi[q] = 0x7fffffff; }
    #pragma unroll
    for (int rr = 0; rr < 16; ++rr) {
      int rowl = sub * 16 + rr;                     // 0..127
      int gi = rowbase + rowl;
      float v = (gi < N) ? reinterpret_cast<float*>(&xt[rowl >> 5][0])[(rowl & 31) * 32 + c]
                         : INF;
      if (v < bk[KNN - 1]) {                        // ascending scan => idx ties kept
        float cv = v; int ci = gi;
        #pragma unroll
        for (int q = 0; q < KNN; ++q) {
          if (cv < bk[q]) {
            float tf = bk[q]; bk[q] = cv; cv = tf;
            int ti = bi[q]; bi[q] = ci; ci = ti;
          }
        }
      }
    }
    // merge 8 sorted lists -> 10 smallest (lex (v,idx)), 8-lane shfl argmin rounds
    int p = 0;
    #pragma unroll
    for (int r = 0; r < KNN; ++r) {
      float hv = (p < KNN) ? bk[p] : INF;
      int hgi = (p < KNN) ? bi[p] : 0x7fffffff;
      float mv = hv; int mgi = hgi;
      #pragma unroll
      for (int off = 1; off < 8; off <<= 1) {
        float ov = __shfl_xor(mv, off); int oi = __shfl_xor(mgi, off);
        if (ov < mv || (ov == mv && oi < mgi)) { mv = ov; mgi = oi; }
      }
      if (p < KNN && hv == mv && hgi == mgi) p++;
      if (sub == 0) {
        candK[((size_t)c * G + blockIdx.x) * KNN + r] = mv;
        candI[((size_t)c * G + blockIdx.x) * KNN + r] = mgi;
      }
    }
  }
}

// ============ fused C-fragments + gram + Gauss-Jordan + scalar stats ============
#define AUGW (NC + NCLS)   // 42
__global__ __launch_bounds__(1024) void k_gramsolve(const float* __restrict__ C,
                                                    const float* __restrict__ W,
                                                    uint4* __restrict__ Chi,
                                                    uint4* __restrict__ Clo,
                                                    float* __restrict__ S,
                                                    float* __restrict__ out, int bs) {
  int tid = threadIdx.x;
  {  // C bf16 hi/lo fragments (wave ws <-> kstep ws)
    int l = tid & 63, ks = tid >> 6;
    int col = l & 31, g = l >> 5;
    uint32_t h[8], lo[8];
    #pragma unroll
    for (int i = 0; i < 8; ++i) {
      int k = ks * 16 + g * 8 + i;
      float x = C[(size_t)k * NC + col];
      uint32_t hb = fbits(x) & 0xFFFF0000u;
      h[i] = hb >> 16;
      lo[i] = fbits(x - bcast(hb)) >> 16;
    }
    Chi[ks * 64 + l] = make_uint4((h[1] << 16) | h[0], (h[3] << 16) | h[2],
                                  (h[5] << 16) | h[4], (h[7] << 16) | h[6]);
    Clo[ks * 64 + l] = make_uint4((lo[1] << 16) | lo[0], (lo[3] << 16) | lo[2],
                                  (lo[5] << 16) | lo[4], (lo[7] << 16) | lo[6]);
  }

  __shared__ float Cs[D * NC];
  __shared__ float Ws[D * NCLS];
  __shared__ float aug[NC * AUGW];
  {
    const float4* C4 = (const float4*)C;  float4* Cs4 = (float4*)Cs;
    Cs4[tid] = C4[tid]; Cs4[tid + 1024] = C4[tid + 1024];
    const float4* W4 = (const float4*)W;  float4* Ws4 = (float4*)Ws;
    if (tid < (D * NCLS) / 4) Ws4[tid] = W4[tid];
  }
  __syncthreads();
  for (int e = tid; e < NC * AUGW; e += 1024) {
    int i = e / AUGW, jj = e % AUGW;
    float acc = 0.f;
    if (jj < NC) {
      #pragma unroll 8
      for (int d = 0; d < D; ++d) acc += Cs[d * NC + i] * Cs[d * NC + jj];
    } else {
      int cls = jj - NC;
      #pragma unroll 8
      for (int d = 0; d < D; ++d) acc += Cs[d * NC + i] * Ws[d * NCLS + cls];
    }
    aug[e] = acc;
  }
  __syncthreads();

  if (tid < NC) {
    int lane = tid;
    float row[AUGW];
    #pragma unroll
    for (int c = 0; c < AUGW; ++c) row[c] = aug[lane * AUGW + c];

    float rsum = 0.f;
    #pragma unroll
    for (int c = 0; c < NC; ++c) rsum += row[c];
    float diag = row[lane];
    #pragma unroll
    for (int off = 16; off; off >>= 1) {
      rsum += __shfl_xor(rsum, off);
      diag += __shfl_xor(diag, off);
    }
    if (lane == 0) {
      out[(size_t)2 * bs * NCLS + 1] = (rsum - diag) / (float)(NC * NC);
      out[(size_t)2 * bs * NCLS + 2] = diag / (float)(NC * NC);
    }

    for (int k = 0; k < NC; ++k) {
      float prow[AUGW];
      #pragma unroll
      for (int c = 0; c < AUGW; ++c) prow[c] = __shfl(row[c], k);
      float pinv = 1.0f / prow[k];
      float f = row[k] * pinv;
      if (lane == k) {
        #pragma unroll
        for (int c = 0; c < AUGW; ++c) row[c] *= pinv;
      } else {
        #pragma unroll
        for (int c = 0; c < AUGW; ++c) row[c] -= f * prow[c];
      }
    }
    #pragma unroll
    for (int c = 0; c < NCLS; ++c) S[lane * NCLS + c] = row[NC + c];
  }
}

// ============ predictions: orig_pred and y_pred ============
__global__ __launch_bounds__(256) void k_pred(const float* __restrict__ X,
                                              const float* __restrict__ C,
                                              const float* __restrict__ W,
                                              const float* __restrict__ bvec,
                                              const float* __restrict__ S,
                                              float* __restrict__ out, int bs) {
  __shared__ float4 Cs4[2048];
  __shared__ float2 Ws2[1280];
  int t = threadIdx.x;
  const float4* C4 = (const float4*)C;
  for (int s = t; s < 2048; s += 256)
    Cs4[s] = C4[(s & ~7) | ((s & 7) ^ ((s >> 6) & 7))];
  const float2* W2 = (const float2*)W;
  for (int s = t; s < 1280; s += 256) Ws2[s] = W2[s];
  __syncthreads();

  int r = blockIdx.x * 8 + (t >> 5);
  int q = t & 31;
  const float4* x4 = reinterpret_cast<const float4*>(X + (size_t)r * D);
  float4 xa = x4[q * 2], xb = x4[q * 2 + 1];

  float a[NC], o[NCLS];
  #pragma unroll
  for (int c = 0; c < NC; ++c) a[c] = 0.f;
  #pragma unroll
  for (int c = 0; c < NCLS; ++c) o[c] = 0.f;

  #pragma unroll
  for (int i = 0; i < 8; ++i) {
    int d = q * 8 + i;
    float xd = (i < 4) ? reinterpret_cast<const float*>(&xa)[i]
                       : reinterpret_cast<const float*>(&xb)[i - 4];
    int sw = (d >> 3) & 7;
    #pragma unroll
    for (int c4 = 0; c4 < 8; ++c4) {
      float4 cv = Cs4[d * 8 + (c4 ^ sw)];
      a[c4 * 4 + 0] += xd * cv.x; a[c4 * 4 + 1] += xd * cv.y;
      a[c4 * 4 + 2] += xd * cv.z; a[c4 * 4 + 3] += xd * cv.w;
    }
    #pragma unroll
    for (int j = 0; j < 5; ++j) {
      float2 wv = Ws2[d * 5 + j];
      o[j * 2 + 0] += xd * wv.x; o[j * 2 + 1] += xd * wv.y;
    }
  }
  #pragma unroll
  for (int off = 1; off < 32; off <<= 1) {
    #pragma unroll
    for (int c = 0; c < NC; ++c) a[c] += __shfl_xor(a[c], off);
    #pragma unroll
    for (int c = 0; c < NCLS; ++c) o[c] += __shfl_xor(o[c], off);
  }
  if (q < NCLS) {
    float b = bvec[q];
    out[(size_t)r * NCLS + q] = o[q] + b;
    float y = b;
    #pragma unroll
    for (int c = 0; c < NC; ++c) y += a[c] * S[c * NCLS + q];
    out[(size_t)bs * NCLS + (size_t)r * NCLS + q] = y;
  }
}

// ============ k_final: merge G*10 candidates/concept + gather + dot ============
__global__ __launch_bounds__(256) void k_final(const float* __restrict__ candK,
                                               const int* __restrict__ candI,
                                               const float* __restrict__ X,
                                               const float* __restrict__ Cc,
                                               float* __restrict__ dots, int G) {
  int j = blockIdx.x, tid = threadIdx.x;
  int M = G * KNN;
  const float INF = 3.4e38f;

  float bk[KNN]; int bi[KNN];
  #pragma unroll
  for (int q = 0; q < KNN; ++q) { bk[q] = INF; bi[q] = 0x7fffffff; }
  for (int e = tid; e < M; e += 256) {
    float v = candK[(size_t)j * M + e];
    int gi = candI[(size_t)j * M + e];
    if (v < bk[KNN - 1] || (v == bk[KNN - 1] && gi < bi[KNN - 1])) {
      float cv = v; int ci = gi;
      #pragma unroll
      for (int q = 0; q < KNN; ++q) {
        bool take = (cv < bk[q]) || (cv == bk[q] && ci < bi[q]);
        if (take) {
          float tf = bk[q]; bk[q] = cv; cv = tf;
          int ti = bi[q]; bi[q] = ci; ci = ti;
        }
      }
    }
  }

  __shared__ float sk[256 * KNN];
  __shared__ int si[256 * KNN];
  __shared__ float wv_[4]; __shared__ int wi_[4];
  __shared__ int topIdx[KNN];
  #pragma unroll
  for (int q = 0; q < KNN; ++q) { sk[tid * KNN + q] = bk[q]; si[tid * KNN + q] = bi[q]; }
  __syncthreads();

  int p = 0;
  int lane = tid & 63, wv = tid >> 6;
  for (int rr = 0; rr < KNN; ++rr) {
    float myv = (p < KNN) ? sk[tid * KNN + p] : INF;
    int mygi = (p < KNN) ? si[tid * KNN + p] : 0x7fffffff;
    float hv = myv; int hgi = mygi;
    #pragma unroll
    for (int off = 32; off; off >>= 1) {
      float ov = __shfl_xor(hv, off); int oi = __shfl_xor(hgi, off);
      if (ov < hv || (ov == hv && oi < hgi)) { hv = ov; hgi = oi; }
    }
    if (lane == 0) { wv_[wv] = hv; wi_[wv] = hgi; }
    __syncthreads();
    float bv = wv_[0]; int bgi = wi_[0];
    #pragma unroll
    for (int w = 1; w < 4; ++w) {
      if (wv_[w] < bv || (wv_[w] == bv && wi_[w] < bgi)) { bv = wv_[w]; bgi = wi_[w]; }
    }
    if (p < KNN && myv == bv && mygi == bgi) p++;
    if (tid == 0) topIdx[rr] = bgi;
    __syncthreads();
  }

  // gather + dot: thread == d
  float cj = Cc[tid * NC + j];
  float acc = 0.f;
  #pragma unroll
  for (int k = 0; k < KNN; ++k) acc += X[(size_t)topIdx[k] * D + tid] * cj;
  acc = wave_sum(acc);
  __shared__ float rsum[4];
  if (lane == 0) rsum[wv] = acc;
  __syncthreads();
  if (tid == 0) dots[j] = (rsum[0] + rsum[1] + rsum[2] + rsum[3]) * (1.0f / KNN);
}

// ============ final scalar: L_sparse_1 = mean(dots) ============
__global__ __launch_bounds__(64) void k_scal(const float* __restrict__ dots,
                                             float* __restrict__ out, int bs) {
  int lane = threadIdx.x;
  float v = (lane < NC) ? dots[lane] : 0.f;
  v = wave_sum(v);
  if (lane == 0) out[(size_t)2 * bs * NCLS] = v / (float)NC;
}

extern "C" void kernel_launch(void* const* d_in, const int* in_sizes, int n_in,
                              void* d_out, int out_size, void* d_ws, size_t ws_size,
                              hipStream_t stream) {
  const float* Xb = (const float*)d_in[0]; // train_embedding [bs][D]
  const float* XN = (const float*)d_in[1]; // train_embeddings [N][D]
  const float* C  = (const float*)d_in[2]; // concept [D][NC]
  const float* W  = (const float*)d_in[3]; // W_hx [D][NCLS]
  const float* bv = (const float*)d_in[4]; // b_hx [NCLS]
  float* out = (float*)d_out;

  int bs = in_sizes[0] / D;   // 4096
  int N  = in_sizes[1] / D;   // 200000
  int G  = (N + KROWS - 1) / KROWS;   // 1563

  float* w = (float*)d_ws;
  size_t offS    = 0;                         // 320 floats
  size_t offChi  = 512;                       // 1024 uint4 (16 KB), 16B-aligned
  size_t offClo  = offChi + 4096;
  size_t offDots = offClo + 4096;             // 32 floats
  size_t offCK   = offDots + 64;              // NC*G*KNN floats
  size_t offCI   = offCK + (size_t)NC * G * KNN;

  float* S     = w + offS;
  uint4* Chi   = (uint4*)(w + offChi);
  uint4* Clo   = (uint4*)(w + offClo);
  float* dots  = w + offDots;
  float* candK = w + offCK;
  int*   candI = (int*)(w + offCI);

  k_gramsolve<<<dim3(1), dim3(1024), 0, stream>>>(C, W, Chi, Clo, S, out, bs);
  k_key<<<dim3(G), dim3(256), 0, stream>>>(XN, Chi, Clo, candK, candI, N, G);
  k_pred<<<dim3(bs / 8), dim3(256), 0, stream>>>(Xb, C, W, bv, S, out, bs);
  k_final<<<dim3(NC), dim3(256), 0, stream>>>(candK, candI, XN, C, dots, G);
  k_scal<<<dim3(1), dim3(64), 0, stream>>>(dots, out, bs);
}

// Round 13
// 214.257 us; speedup vs baseline: 1.0490x; 1.0490x over previous
//
#include <hip/hip_runtime.h>
#include <cstdint>

#define D 256
#define NC 32
#define NCLS 10
#define KNN 10
#define KROWS 128

typedef float f32x4 __attribute__((ext_vector_type(4)));
typedef short short8v __attribute__((ext_vector_type(8)));
typedef const __attribute__((address_space(1))) unsigned int* gp1_t;
typedef __attribute__((address_space(3))) unsigned int* sp3_t;

__device__ __forceinline__ float wave_sum(float v) {
  #pragma unroll
  for (int off = 32; off; off >>= 1) v += __shfl_xor(v, off);
  return v;
}

__device__ __forceinline__ uint32_t fbits(float x) { return __builtin_bit_cast(uint32_t, x); }
__device__ __forceinline__ float bcast(uint32_t b) { return __builtin_bit_cast(float, b); }

// ============ k_key: 16x16x32 MFMA, X direct-to-register, fused block-top10 ============
// 512 threads = 8 waves, 128 rows/block; wave w rows w*16..+15.
// A-frag = lane(row=l&15, k=(l>>4)*8+i): exactly 2 float4 loads/K-step, 4 lanes
// consume each 128B line fully. NO X-LDS, NO barriers in main loop -> compiler
// pipelines the 16 independent loads. C-frags (2 tiles x 8 ks, bf16 hi/lo) in LDS,
// broadcast reads. 3 MFMA/tile/ks (hi*hi; both mixed terms share one acc).
__global__ __launch_bounds__(512) void k_key(const float* __restrict__ X,
                                             const uint4* __restrict__ Chi,
                                             const uint4* __restrict__ Clo,
                                             float* __restrict__ candK,
                                             int* __restrict__ candI,
                                             int N, int G) {
  __shared__ uint4 shm[2048];            // 32 KB: [0,1024)=Chi frags, [1024,2048)=Clo
  int t = threadIdx.x;
  int lane = t & 63;
  int wvu = __builtin_amdgcn_readfirstlane(t >> 6);   // 0..7
  int rowbase = blockIdx.x * KROWS;

  // stage C fragments once (per-lane global src, uniform LDS base)
  #pragma unroll
  for (int i = 0; i < 2; ++i) {
    const uint4* srcH = Chi + wvu * 128 + i * 64 + lane;
    __builtin_amdgcn_global_load_lds((gp1_t)(const void*)srcH,
        (sp3_t)(void*)(&shm[wvu * 128 + i * 64]), 16, 0, 0);
    const uint4* srcL = Clo + wvu * 128 + i * 64 + lane;
    __builtin_amdgcn_global_load_lds((gp1_t)(const void*)srcL,
        (sp3_t)(void*)(&shm[1024 + wvu * 128 + i * 64]), 16, 0, 0);
  }
  __syncthreads();

  int r16 = lane & 15;
  int grow = rowbase + wvu * 16 + r16; if (grow >= N) grow = N - 1;
  const float* xp = X + (size_t)grow * D + ((lane >> 4) * 8);

  f32x4 aH0, aM0, aH1, aM1;
  #pragma unroll
  for (int i = 0; i < 4; ++i) { aH0[i] = 0.f; aM0[i] = 0.f; aH1[i] = 0.f; aM1[i] = 0.f; }
  float x2 = 0.f;

  #pragma unroll
  for (int ks = 0; ks < 8; ++ks) {
    float4 xa = *reinterpret_cast<const float4*>(xp + ks * 32);
    float4 xb = *reinterpret_cast<const float4*>(xp + ks * 32 + 4);
    float xs[8] = {xa.x, xa.y, xa.z, xa.w, xb.x, xb.y, xb.z, xb.w};
    uint32_t hp[4], lp[4];
    #pragma unroll
    for (int p = 0; p < 4; ++p) {
      float x0 = xs[2 * p], x1 = xs[2 * p + 1];
      x2 = fmaf(x0, x0, x2); x2 = fmaf(x1, x1, x2);
      uint32_t h0 = fbits(x0) & 0xFFFF0000u, h1 = fbits(x1) & 0xFFFF0000u;
      hp[p] = h1 | (h0 >> 16);
      float r0 = x0 - bcast(h0), r1 = x1 - bcast(h1);
      lp[p] = (fbits(r1) & 0xFFFF0000u) | (fbits(r0) >> 16);
    }
    short8v xh = __builtin_bit_cast(short8v, make_uint4(hp[0], hp[1], hp[2], hp[3]));
    short8v xl = __builtin_bit_cast(short8v, make_uint4(lp[0], lp[1], lp[2], lp[3]));
    short8v b0h = __builtin_bit_cast(short8v, shm[ks * 64 + lane]);          // tile0 hi
    short8v b1h = __builtin_bit_cast(short8v, shm[(8 + ks) * 64 + lane]);    // tile1 hi
    short8v b0l = __builtin_bit_cast(short8v, shm[1024 + ks * 64 + lane]);
    short8v b1l = __builtin_bit_cast(short8v, shm[1024 + (8 + ks) * 64 + lane]);
    aH0 = __builtin_amdgcn_mfma_f32_16x16x32_bf16(xh, b0h, aH0, 0, 0, 0);
    aM0 = __builtin_amdgcn_mfma_f32_16x16x32_bf16(xh, b0l, aM0, 0, 0, 0);
    aM0 = __builtin_amdgcn_mfma_f32_16x16x32_bf16(xl, b0h, aM0, 0, 0, 0);
    aH1 = __builtin_amdgcn_mfma_f32_16x16x32_bf16(xh, b1h, aH1, 0, 0, 0);
    aM1 = __builtin_amdgcn_mfma_f32_16x16x32_bf16(xh, b1l, aM1, 0, 0, 0);
    aM1 = __builtin_amdgcn_mfma_f32_16x16x32_bf16(xl, b1h, aM1, 0, 0, 0);
  }

  // full |x|^2 of row r16: sum the 4 k-group lanes
  x2 += __shfl_xor(x2, 16);
  x2 += __shfl_xor(x2, 32);          // lane l now holds x2 of row (l&15)

  // keys -> LDS transpose buffer (aliases dead C-frag region)
  __syncthreads();                    // all waves done reading shm frags
  float* klb = reinterpret_cast<float*>(shm);   // klb[row*33 + c], 128x33 = 16.9 KB
  #pragma unroll
  for (int i = 0; i < 4; ++i) {
    int m = (lane >> 4) * 4 + i;                 // X-row within wave tile (D-map m89/m91)
    float x2m = __shfl(x2, m);                   // x2 of row m (lane m holds it)
    int rowl = wvu * 16 + m;
    klb[rowl * 33 + r16]      = fmaf(-2.f, aH0[i] + aM0[i], x2m);   // concept r16
    klb[rowl * 33 + 16 + r16] = fmaf(-2.f, aH1[i] + aM1[i], x2m);   // concept 16+r16
  }
  __syncthreads();

  // block top-10 per concept: team = 16 threads, c = t>>4, sub = t&15, 8 rows each
  {
    int c = t >> 4, sub = t & 15;
    const float INF = 3.4e38f;
    float bk[8]; int bi[8];
    #pragma unroll
    for (int q = 0; q < 8; ++q) { bk[q] = INF; bi[q] = 0x7fffffff; }
    #pragma unroll
    for (int rr = 0; rr < 8; ++rr) {
      int rowl = sub * 8 + rr;
      int gi = rowbase + rowl;
      float v = (gi < N) ? klb[rowl * 33 + c] : INF;
      // full insertion (8 slots, 8 values; lex (v,idx))
      float cv = v; int ci = gi;
      #pragma unroll
      for (int q = 0; q < 8; ++q) {
        bool take = (cv < bk[q]) || (cv == bk[q] && ci < bi[q]);
        if (take) {
          float tf = bk[q]; bk[q] = cv; cv = tf;
          int ti = bi[q]; bi[q] = ci; ci = ti;
        }
      }
    }
    // merge 16 sorted 8-lists -> top-10 via shfl argmin rounds (team-local, xor<16)
    int p = 0;
    #pragma unroll
    for (int r = 0; r < KNN; ++r) {
      float hv = (p < 8) ? bk[p] : INF;
      int hgi = (p < 8) ? bi[p] : 0x7fffffff;
      float mv = hv; int mgi = hgi;
      #pragma unroll
      for (int off = 1; off < 16; off <<= 1) {
        float ov = __shfl_xor(mv, off); int oi = __shfl_xor(mgi, off);
        if (ov < mv || (ov == mv && oi < mgi)) { mv = ov; mgi = oi; }
      }
      if (p < 8 && hv == mv && hgi == mgi) p++;
      if (sub == 0) {
        candK[((size_t)c * G + blockIdx.x) * KNN + r] = mv;
        candI[((size_t)c * G + blockIdx.x) * KNN + r] = mgi;
      }
    }
  }
}

// ============ fused C-fragments + gram + Gauss-Jordan + scalar stats ============
#define AUGW (NC + NCLS)   // 42
__global__ __launch_bounds__(1024) void k_gramsolve(const float* __restrict__ C,
                                                    const float* __restrict__ W,
                                                    uint4* __restrict__ Chi,
                                                    uint4* __restrict__ Clo,
                                                    float* __restrict__ S,
                                                    float* __restrict__ out, int bs) {
  int tid = threadIdx.x;
  {  // C bf16 hi/lo B-fragments for 16x16x32: q = tile*8+ks; lane: col=tile*16+(l&15),
     // k = ks*32 + ((l>>4)&3)*8 + i
    int l = tid & 63, q = tid >> 6;          // q 0..15
    int tile = q >> 3, ks = q & 7;
    int col = tile * 16 + (l & 15), kg = (l >> 4) & 3;
    uint32_t h[8], lo[8];
    #pragma unroll
    for (int i = 0; i < 8; ++i) {
      int k = ks * 32 + kg * 8 + i;
      float x = C[(size_t)k * NC + col];
      uint32_t hb = fbits(x) & 0xFFFF0000u;
      h[i] = hb >> 16;
      lo[i] = fbits(x - bcast(hb)) >> 16;
    }
    Chi[q * 64 + l] = make_uint4((h[1] << 16) | h[0], (h[3] << 16) | h[2],
                                 (h[5] << 16) | h[4], (h[7] << 16) | h[6]);
    Clo[q * 64 + l] = make_uint4((lo[1] << 16) | lo[0], (lo[3] << 16) | lo[2],
                                 (lo[5] << 16) | lo[4], (lo[7] << 16) | lo[6]);
  }

  __shared__ float Cs[D * NC];
  __shared__ float Ws[D * NCLS];
  __shared__ float aug[NC * AUGW];
  {
    const float4* C4 = (const float4*)C;  float4* Cs4 = (float4*)Cs;
    Cs4[tid] = C4[tid]; Cs4[tid + 1024] = C4[tid + 1024];
    const float4* W4 = (const float4*)W;  float4* Ws4 = (float4*)Ws;
    if (tid < (D * NCLS) / 4) Ws4[tid] = W4[tid];
  }
  __syncthreads();
  for (int e = tid; e < NC * AUGW; e += 1024) {
    int i = e / AUGW, jj = e % AUGW;
    float acc = 0.f;
    if (jj < NC) {
      #pragma unroll 8
      for (int d = 0; d < D; ++d) acc += Cs[d * NC + i] * Cs[d * NC + jj];
    } else {
      int cls = jj - NC;
      #pragma unroll 8
      for (int d = 0; d < D; ++d) acc += Cs[d * NC + i] * Ws[d * NCLS + cls];
    }
    aug[e] = acc;
  }
  __syncthreads();

  if (tid < NC) {
    int lane = tid;
    float row[AUGW];
    #pragma unroll
    for (int c = 0; c < AUGW; ++c) row[c] = aug[lane * AUGW + c];

    float rsum = 0.f;
    #pragma unroll
    for (int c = 0; c < NC; ++c) rsum += row[c];
    float diag = row[lane];
    #pragma unroll
    for (int off = 16; off; off >>= 1) {
      rsum += __shfl_xor(rsum, off);
      diag += __shfl_xor(diag, off);
    }
    if (lane == 0) {
      out[(size_t)2 * bs * NCLS + 1] = (rsum - diag) / (float)(NC * NC);
      out[(size_t)2 * bs * NCLS + 2] = diag / (float)(NC * NC);
    }

    for (int k = 0; k < NC; ++k) {
      float prow[AUGW];
      #pragma unroll
      for (int c = 0; c < AUGW; ++c) prow[c] = __shfl(row[c], k);
      float pinv = 1.0f / prow[k];
      float f = row[k] * pinv;
      if (lane == k) {
        #pragma unroll
        for (int c = 0; c < AUGW; ++c) row[c] *= pinv;
      } else {
        #pragma unroll
        for (int c = 0; c < AUGW; ++c) row[c] -= f * prow[c];
      }
    }
    #pragma unroll
    for (int c = 0; c < NCLS; ++c) S[lane * NCLS + c] = row[NC + c];
  }
}

// ============ predictions: orig_pred and y_pred ============
__global__ __launch_bounds__(256) void k_pred(const float* __restrict__ X,
                                              const float* __restrict__ C,
                                              const float* __restrict__ W,
                                              const float* __restrict__ bvec,
                                              const float* __restrict__ S,
                                              float* __restrict__ out, int bs) {
  __shared__ float4 Cs4[2048];
  __shared__ float2 Ws2[1280];
  int t = threadIdx.x;
  const float4* C4 = (const float4*)C;
  for (int s = t; s < 2048; s += 256)
    Cs4[s] = C4[(s & ~7) | ((s & 7) ^ ((s >> 6) & 7))];
  const float2* W2 = (const float2*)W;
  for (int s = t; s < 1280; s += 256) Ws2[s] = W2[s];
  __syncthreads();

  int r = blockIdx.x * 8 + (t >> 5);
  int q = t & 31;
  const float4* x4 = reinterpret_cast<const float4*>(X + (size_t)r * D);
  float4 xa = x4[q * 2], xb = x4[q * 2 + 1];

  float a[NC], o[NCLS];
  #pragma unroll
  for (int c = 0; c < NC; ++c) a[c] = 0.f;
  #pragma unroll
  for (int c = 0; c < NCLS; ++c) o[c] = 0.f;

  #pragma unroll
  for (int i = 0; i < 8; ++i) {
    int d = q * 8 + i;
    float xd = (i < 4) ? reinterpret_cast<const float*>(&xa)[i]
                       : reinterpret_cast<const float*>(&xb)[i - 4];
    int sw = (d >> 3) & 7;
    #pragma unroll
    for (int c4 = 0; c4 < 8; ++c4) {
      float4 cv = Cs4[d * 8 + (c4 ^ sw)];
      a[c4 * 4 + 0] += xd * cv.x; a[c4 * 4 + 1] += xd * cv.y;
      a[c4 * 4 + 2] += xd * cv.z; a[c4 * 4 + 3] += xd * cv.w;
    }
    #pragma unroll
    for (int j = 0; j < 5; ++j) {
      float2 wv = Ws2[d * 5 + j];
      o[j * 2 + 0] += xd * wv.x; o[j * 2 + 1] += xd * wv.y;
    }
  }
  #pragma unroll
  for (int off = 1; off < 32; off <<= 1) {
    #pragma unroll
    for (int c = 0; c < NC; ++c) a[c] += __shfl_xor(a[c], off);
    #pragma unroll
    for (int c = 0; c < NCLS; ++c) o[c] += __shfl_xor(o[c], off);
  }
  if (q < NCLS) {
    float b = bvec[q];
    out[(size_t)r * NCLS + q] = o[q] + b;
    float y = b;
    #pragma unroll
    for (int c = 0; c < NC; ++c) y += a[c] * S[c * NCLS + q];
    out[(size_t)bs * NCLS + (size_t)r * NCLS + q] = y;
  }
}

// ============ k_final: merge G*10 candidates/concept + gather + dot ============
__global__ __launch_bounds__(256) void k_final(const float* __restrict__ candK,
                                               const int* __restrict__ candI,
                                               const float* __restrict__ X,
                                               const float* __restrict__ Cc,
                                               float* __restrict__ dots, int G) {
  int j = blockIdx.x, tid = threadIdx.x;
  int M = G * KNN;
  const float INF = 3.4e38f;

  float bk[KNN]; int bi[KNN];
  #pragma unroll
  for (int q = 0; q < KNN; ++q) { bk[q] = INF; bi[q] = 0x7fffffff; }
  for (int e = tid; e < M; e += 256) {
    float v = candK[(size_t)j * M + e];
    int gi = candI[(size_t)j * M + e];
    if (v < bk[KNN - 1] || (v == bk[KNN - 1] && gi < bi[KNN - 1])) {
      float cv = v; int ci = gi;
      #pragma unroll
      for (int q = 0; q < KNN; ++q) {
        bool take = (cv < bk[q]) || (cv == bk[q] && ci < bi[q]);
        if (take) {
          float tf = bk[q]; bk[q] = cv; cv = tf;
          int ti = bi[q]; bi[q] = ci; ci = ti;
        }
      }
    }
  }

  __shared__ float sk[256 * KNN];
  __shared__ int si[256 * KNN];
  __shared__ float wv_[4]; __shared__ int wi_[4];
  __shared__ int topIdx[KNN];
  #pragma unroll
  for (int q = 0; q < KNN; ++q) { sk[tid * KNN + q] = bk[q]; si[tid * KNN + q] = bi[q]; }
  __syncthreads();

  int p = 0;
  int lane = tid & 63, wv = tid >> 6;
  for (int rr = 0; rr < KNN; ++rr) {
    float myv = (p < KNN) ? sk[tid * KNN + p] : INF;
    int mygi = (p < KNN) ? si[tid * KNN + p] : 0x7fffffff;
    float hv = myv; int hgi = mygi;
    #pragma unroll
    for (int off = 32; off; off >>= 1) {
      float ov = __shfl_xor(hv, off); int oi = __shfl_xor(hgi, off);
      if (ov < hv || (ov == hv && oi < hgi)) { hv = ov; hgi = oi; }
    }
    if (lane == 0) { wv_[wv] = hv; wi_[wv] = hgi; }
    __syncthreads();
    float bv = wv_[0]; int bgi = wi_[0];
    #pragma unroll
    for (int w = 1; w < 4; ++w) {
      if (wv_[w] < bv || (wv_[w] == bv && wi_[w] < bgi)) { bv = wv_[w]; bgi = wi_[w]; }
    }
    if (p < KNN && myv == bv && mygi == bgi) p++;
    if (tid == 0) topIdx[rr] = bgi;
    __syncthreads();
  }

  float cj = Cc[tid * NC + j];
  float acc = 0.f;
  #pragma unroll
  for (int k = 0; k < KNN; ++k) acc += X[(size_t)topIdx[k] * D + tid] * cj;
  acc = wave_sum(acc);
  __shared__ float rsum[4];
  if (lane == 0) rsum[wv] = acc;
  __syncthreads();
  if (tid == 0) dots[j] = (rsum[0] + rsum[1] + rsum[2] + rsum[3]) * (1.0f / KNN);
}

// ============ final scalar: L_sparse_1 = mean(dots) ============
__global__ __launch_bounds__(64) void k_scal(const float* __restrict__ dots,
                                             float* __restrict__ out, int bs) {
  int lane = threadIdx.x;
  float v = (lane < NC) ? dots[lane] : 0.f;
  v = wave_sum(v);
  if (lane == 0) out[(size_t)2 * bs * NCLS] = v / (float)NC;
}

extern "C" void kernel_launch(void* const* d_in, const int* in_sizes, int n_in,
                              void* d_out, int out_size, void* d_ws, size_t ws_size,
                              hipStream_t stream) {
  const float* Xb = (const float*)d_in[0]; // train_embedding [bs][D]
  const float* XN = (const float*)d_in[1]; // train_embeddings [N][D]
  const float* C  = (const float*)d_in[2]; // concept [D][NC]
  const float* W  = (const float*)d_in[3]; // W_hx [D][NCLS]
  const float* bv = (const float*)d_in[4]; // b_hx [NCLS]
  float* out = (float*)d_out;

  int bs = in_sizes[0] / D;   // 4096
  int N  = in_sizes[1] / D;   // 200000
  int G  = (N + KROWS - 1) / KROWS;   // 1563

  float* w = (float*)d_ws;
  size_t offS    = 0;                         // 320 floats
  size_t offChi  = 512;                       // 1024 uint4 (16 KB), 16B-aligned
  size_t offClo  = offChi + 4096;
  size_t offDots = offClo + 4096;             // 32 floats
  size_t offCK   = offDots + 64;              // NC*G*KNN floats
  size_t offCI   = offCK + (size_t)NC * G * KNN;

  float* S     = w + offS;
  uint4* Chi   = (uint4*)(w + offChi);
  uint4* Clo   = (uint4*)(w + offClo);
  float* dots  = w + offDots;
  float* candK = w + offCK;
  int*   candI = (int*)(w + offCI);

  k_gramsolve<<<dim3(1), dim3(1024), 0, stream>>>(C, W, Chi, Clo, S, out, bs);
  k_key<<<dim3(G), dim3(512), 0, stream>>>(XN, Chi, Clo, candK, candI, N, G);
  k_pred<<<dim3(bs / 8), dim3(256), 0, stream>>>(Xb, C, W, bv, S, out, bs);
  k_final<<<dim3(NC), dim3(256), 0, stream>>>(candK, candI, XN, C, dots, G);
  k_scal<<<dim3(1), dim3(64), 0, stream>>>(dots, out, bs);
}

// Round 14
// 172.243 us; speedup vs baseline: 1.3049x; 1.2439x over previous
//
#include <hip/hip_runtime.h>
#include <cstdint>

#define D 256
#define NC 32
#define NCLS 10
#define KNN 10
#define KROWS 128
#define CTS 260   // padded LDS row stride for transposed C/W (bank-spread)

typedef float f32x4 __attribute__((ext_vector_type(4)));
typedef float f4v __attribute__((ext_vector_type(4)));
typedef short short8v __attribute__((ext_vector_type(8)));

__device__ __forceinline__ float wave_sum(float v) {
  #pragma unroll
  for (int off = 32; off; off >>= 1) v += __shfl_xor(v, off);
  return v;
}

__device__ __forceinline__ uint32_t fbits(float x) { return __builtin_bit_cast(uint32_t, x); }
__device__ __forceinline__ float bcast(uint32_t b) { return __builtin_bit_cast(float, b); }

// ============ k_key: 16x16x32 MFMA, X direct (nontemporal), self C-frags ============
// 512 thr = 8 waves, 128 rows/block; wave w rows w*16..+15.
// Per block: compute own bf16 hi/lo C-fragments into LDS (C is L2-hot), then
// barrier-free main loop: per ks 2 nt float4 loads + convert + 4 LDS frag reads
// + 6 MFMA. Epilogue: keys->LDS transpose, fused block-top-10 per concept.
__global__ __launch_bounds__(512, 4) void k_key(const float* __restrict__ X,
                                                const float* __restrict__ C,
                                                float* __restrict__ candK,
                                                int* __restrict__ candI,
                                                int N, int G) {
  __shared__ uint4 shm[2048];            // 32 KB: [0,1024)=hi frags, [1024,2048)=lo
  int t = threadIdx.x;
  int lane = t & 63;
  int wvu = __builtin_amdgcn_readfirstlane(t >> 6);   // 0..7
  int rowbase = blockIdx.x * KROWS;

  // --- self-compute C fragments (B-frag for 16x16x32): entry e: q=e>>6, l=e&63;
  //     tile=q>>3, ks=q&7; col=tile*16+(l&15); kg=(l>>4)&3; k=ks*32+kg*8+i ---
  #pragma unroll
  for (int e0 = 0; e0 < 1024; e0 += 512) {
    int e = e0 + t;
    int q = e >> 6, l = e & 63;
    int tile = q >> 3, ksq = q & 7;
    int col = tile * 16 + (l & 15), kg = (l >> 4) & 3;
    uint32_t h[8], lo[8];
    #pragma unroll
    for (int i = 0; i < 8; ++i) {
      int k = ksq * 32 + kg * 8 + i;
      float x = C[(size_t)k * NC + col];
      uint32_t hb = fbits(x) & 0xFFFF0000u;
      h[i] = hb >> 16;
      lo[i] = fbits(x - bcast(hb)) >> 16;
    }
    shm[e] = make_uint4((h[1] << 16) | h[0], (h[3] << 16) | h[2],
                        (h[5] << 16) | h[4], (h[7] << 16) | h[6]);
    shm[1024 + e] = make_uint4((lo[1] << 16) | lo[0], (lo[3] << 16) | lo[2],
                               (lo[5] << 16) | lo[4], (lo[7] << 16) | lo[6]);
  }
  __syncthreads();

  int r16 = lane & 15;
  int grow = rowbase + wvu * 16 + r16; if (grow >= N) grow = N - 1;
  const float* xp = X + (size_t)grow * D + ((lane >> 4) * 8);

  f32x4 aH0, aM0, aH1, aM1;
  #pragma unroll
  for (int i = 0; i < 4; ++i) { aH0[i] = 0.f; aM0[i] = 0.f; aH1[i] = 0.f; aM1[i] = 0.f; }
  float x2 = 0.f;

  #pragma unroll
  for (int ks = 0; ks < 8; ++ks) {
    f4v xa = __builtin_nontemporal_load(reinterpret_cast<const f4v*>(xp + ks * 32));
    f4v xb = __builtin_nontemporal_load(reinterpret_cast<const f4v*>(xp + ks * 32 + 4));
    float xs[8] = {xa[0], xa[1], xa[2], xa[3], xb[0], xb[1], xb[2], xb[3]};
    uint32_t hp[4], lp[4];
    #pragma unroll
    for (int p = 0; p < 4; ++p) {
      float x0 = xs[2 * p], x1 = xs[2 * p + 1];
      x2 = fmaf(x0, x0, x2); x2 = fmaf(x1, x1, x2);
      uint32_t h0 = fbits(x0) & 0xFFFF0000u, h1 = fbits(x1) & 0xFFFF0000u;
      hp[p] = h1 | (h0 >> 16);
      float r0 = x0 - bcast(h0), r1 = x1 - bcast(h1);
      lp[p] = (fbits(r1) & 0xFFFF0000u) | (fbits(r0) >> 16);
    }
    short8v xh = __builtin_bit_cast(short8v, make_uint4(hp[0], hp[1], hp[2], hp[3]));
    short8v xl = __builtin_bit_cast(short8v, make_uint4(lp[0], lp[1], lp[2], lp[3]));
    short8v b0h = __builtin_bit_cast(short8v, shm[ks * 64 + lane]);
    short8v b1h = __builtin_bit_cast(short8v, shm[(8 + ks) * 64 + lane]);
    short8v b0l = __builtin_bit_cast(short8v, shm[1024 + ks * 64 + lane]);
    short8v b1l = __builtin_bit_cast(short8v, shm[1024 + (8 + ks) * 64 + lane]);
    aH0 = __builtin_amdgcn_mfma_f32_16x16x32_bf16(xh, b0h, aH0, 0, 0, 0);
    aM0 = __builtin_amdgcn_mfma_f32_16x16x32_bf16(xh, b0l, aM0, 0, 0, 0);
    aM0 = __builtin_amdgcn_mfma_f32_16x16x32_bf16(xl, b0h, aM0, 0, 0, 0);
    aH1 = __builtin_amdgcn_mfma_f32_16x16x32_bf16(xh, b1h, aH1, 0, 0, 0);
    aM1 = __builtin_amdgcn_mfma_f32_16x16x32_bf16(xh, b1l, aM1, 0, 0, 0);
    aM1 = __builtin_amdgcn_mfma_f32_16x16x32_bf16(xl, b1h, aM1, 0, 0, 0);
  }

  x2 += __shfl_xor(x2, 16);
  x2 += __shfl_xor(x2, 32);          // lane l holds x2 of row (l&15)

  __syncthreads();                    // all waves done reading frags
  float* klb = reinterpret_cast<float*>(shm);   // klb[row*33 + c], 128x33
  #pragma unroll
  for (int i = 0; i < 4; ++i) {
    int m = (lane >> 4) * 4 + i;                 // X-row within wave tile (m89/m91)
    float x2m = __shfl(x2, m);
    int rowl = wvu * 16 + m;
    klb[rowl * 33 + r16]      = fmaf(-2.f, aH0[i] + aM0[i], x2m);
    klb[rowl * 33 + 16 + r16] = fmaf(-2.f, aH1[i] + aM1[i], x2m);
  }
  __syncthreads();

  // block top-10 per concept: team = 16 threads, c = t>>4, sub = t&15, 8 rows each
  {
    int c = t >> 4, sub = t & 15;
    const float INF = 3.4e38f;
    float bk[8]; int bi[8];
    #pragma unroll
    for (int q = 0; q < 8; ++q) { bk[q] = INF; bi[q] = 0x7fffffff; }
    #pragma unroll
    for (int rr = 0; rr < 8; ++rr) {
      int rowl = sub * 8 + rr;
      int gi = rowbase + rowl;
      float v = (gi < N) ? klb[rowl * 33 + c] : INF;
      float cv = v; int ci = gi;
      #pragma unroll
      for (int q = 0; q < 8; ++q) {
        bool take = (cv < bk[q]) || (cv == bk[q] && ci < bi[q]);
        if (take) {
          float tf = bk[q]; bk[q] = cv; cv = tf;
          int ti = bi[q]; bi[q] = ci; ci = ti;
        }
      }
    }
    int p = 0;
    #pragma unroll
    for (int r = 0; r < KNN; ++r) {
      float hv = (p < 8) ? bk[p] : INF;
      int hgi = (p < 8) ? bi[p] : 0x7fffffff;
      float mv = hv; int mgi = hgi;
      #pragma unroll
      for (int off = 1; off < 16; off <<= 1) {
        float ov = __shfl_xor(mv, off); int oi = __shfl_xor(mgi, off);
        if (ov < mv || (ov == mv && oi < mgi)) { mv = ov; mgi = oi; }
      }
      if (p < 8 && hv == mv && hgi == mgi) p++;
      if (sub == 0) {
        candK[((size_t)c * G + blockIdx.x) * KNN + r] = mv;
        candI[((size_t)c * G + blockIdx.x) * KNN + r] = mgi;
      }
    }
  }
}

// ============ gram + Gauss-Jordan + scalar stats (transposed-LDS dots) ============
#define AUGW (NC + NCLS)   // 42
__global__ __launch_bounds__(1024) void k_gramsolve(const float* __restrict__ C,
                                                    const float* __restrict__ W,
                                                    float* __restrict__ S,
                                                    float* __restrict__ out, int bs) {
  __shared__ float T[(NC + NCLS) * CTS];   // rows 0-31 = C^T, rows 32-41 = W^T
  __shared__ float aug[NC * AUGW];
  int tid = threadIdx.x;

  const float4* C4 = (const float4*)C;
  for (int s = tid; s < 2048; s += 1024) {
    float4 v = C4[s];                     // d = s>>3, cols (s&7)*4..+3
    int d = s >> 3, c0 = (s & 7) * 4;
    T[(c0 + 0) * CTS + d] = v.x; T[(c0 + 1) * CTS + d] = v.y;
    T[(c0 + 2) * CTS + d] = v.z; T[(c0 + 3) * CTS + d] = v.w;
  }
  const float2* W2 = (const float2*)W;
  for (int s = tid; s < 1280; s += 1024) {
    float2 v = W2[s];                     // d = s/5, cls (s%5)*2..+1
    int d = s / 5, c0 = (s % 5) * 2;
    T[(NC + c0) * CTS + d] = v.x; T[(NC + c0 + 1) * CTS + d] = v.y;
  }
  __syncthreads();

  // aug[i][j]: wave w -> rows w and w+16; lane j -> column (j<42)
  int lane = tid & 63, wv = tid >> 6;
  #pragma unroll
  for (int half = 0; half < 2; ++half) {
    int i = wv + half * 16;
    if (lane < AUGW) {
      const float4* ri = (const float4*)&T[i * CTS];       // uniform -> broadcast
      const float4* rj = (const float4*)&T[lane * CTS];    // j-spread, conflict-free
      float acc = 0.f;
      #pragma unroll 8
      for (int d4 = 0; d4 < 64; ++d4) {
        float4 a = ri[d4], b = rj[d4];
        acc += a.x * b.x + a.y * b.y + a.z * b.z + a.w * b.w;
      }
      aug[i * AUGW + lane] = acc;
    }
  }
  __syncthreads();

  if (tid < NC) {
    int l2 = tid;
    float row[AUGW];
    #pragma unroll
    for (int c = 0; c < AUGW; ++c) row[c] = aug[l2 * AUGW + c];

    float rsum = 0.f;
    #pragma unroll
    for (int c = 0; c < NC; ++c) rsum += row[c];
    float diag = row[l2];
    #pragma unroll
    for (int off = 16; off; off >>= 1) {
      rsum += __shfl_xor(rsum, off);
      diag += __shfl_xor(diag, off);
    }
    if (l2 == 0) {
      out[(size_t)2 * bs * NCLS + 1] = (rsum - diag) / (float)(NC * NC);
      out[(size_t)2 * bs * NCLS + 2] = diag / (float)(NC * NC);
    }

    for (int k = 0; k < NC; ++k) {
      float prow[AUGW];
      #pragma unroll
      for (int c = 0; c < AUGW; ++c) prow[c] = __shfl(row[c], k);
      float pinv = 1.0f / prow[k];
      float f = row[k] * pinv;
      if (l2 == k) {
        #pragma unroll
        for (int c = 0; c < AUGW; ++c) row[c] *= pinv;
      } else {
        #pragma unroll
        for (int c = 0; c < AUGW; ++c) row[c] -= f * prow[c];
      }
    }
    #pragma unroll
    for (int c = 0; c < NCLS; ++c) S[l2 * NCLS + c] = row[NC + c];
  }
}

// ============ predictions: orig_pred and y_pred ============
__global__ __launch_bounds__(256) void k_pred(const float* __restrict__ X,
                                              const float* __restrict__ C,
                                              const float* __restrict__ W,
                                              const float* __restrict__ bvec,
                                              const float* __restrict__ S,
                                              float* __restrict__ out, int bs) {
  __shared__ float4 Cs4[2048];
  __shared__ float2 Ws2[1280];
  int t = threadIdx.x;
  const float4* C4 = (const float4*)C;
  for (int s = t; s < 2048; s += 256)
    Cs4[s] = C4[(s & ~7) | ((s & 7) ^ ((s >> 6) & 7))];
  const float2* W2 = (const float2*)W;
  for (int s = t; s < 1280; s += 256) Ws2[s] = W2[s];
  __syncthreads();

  int r = blockIdx.x * 8 + (t >> 5);
  int q = t & 31;
  const float4* x4 = reinterpret_cast<const float4*>(X + (size_t)r * D);
  float4 xa = x4[q * 2], xb = x4[q * 2 + 1];

  float a[NC], o[NCLS];
  #pragma unroll
  for (int c = 0; c < NC; ++c) a[c] = 0.f;
  #pragma unroll
  for (int c = 0; c < NCLS; ++c) o[c] = 0.f;

  #pragma unroll
  for (int i = 0; i < 8; ++i) {
    int d = q * 8 + i;
    float xd = (i < 4) ? reinterpret_cast<const float*>(&xa)[i]
                       : reinterpret_cast<const float*>(&xb)[i - 4];
    int sw = (d >> 3) & 7;
    #pragma unroll
    for (int c4 = 0; c4 < 8; ++c4) {
      float4 cv = Cs4[d * 8 + (c4 ^ sw)];
      a[c4 * 4 + 0] += xd * cv.x; a[c4 * 4 + 1] += xd * cv.y;
      a[c4 * 4 + 2] += xd * cv.z; a[c4 * 4 + 3] += xd * cv.w;
    }
    #pragma unroll
    for (int j = 0; j < 5; ++j) {
      float2 wv = Ws2[d * 5 + j];
      o[j * 2 + 0] += xd * wv.x; o[j * 2 + 1] += xd * wv.y;
    }
  }
  #pragma unroll
  for (int off = 1; off < 32; off <<= 1) {
    #pragma unroll
    for (int c = 0; c < NC; ++c) a[c] += __shfl_xor(a[c], off);
    #pragma unroll
    for (int c = 0; c < NCLS; ++c) o[c] += __shfl_xor(o[c], off);
  }
  if (q < NCLS) {
    float b = bvec[q];
    out[(size_t)r * NCLS + q] = o[q] + b;
    float y = b;
    #pragma unroll
    for (int c = 0; c < NC; ++c) y += a[c] * S[c * NCLS + q];
    out[(size_t)bs * NCLS + (size_t)r * NCLS + q] = y;
  }
}

// ============ k_final: merge G*10 candidates/concept + gather + dot ============
__global__ __launch_bounds__(512) void k_final(const float* __restrict__ candK,
                                               const int* __restrict__ candI,
                                               const float* __restrict__ X,
                                               const float* __restrict__ Cc,
                                               float* __restrict__ dots, int G) {
  int j = blockIdx.x, tid = threadIdx.x;
  int M = G * KNN;
  const float INF = 3.4e38f;

  float bk[KNN]; int bi[KNN];
  #pragma unroll
  for (int q = 0; q < KNN; ++q) { bk[q] = INF; bi[q] = 0x7fffffff; }
  for (int e = tid; e < M; e += 512) {
    float v = candK[(size_t)j * M + e];
    int gi = candI[(size_t)j * M + e];
    if (v < bk[KNN - 1] || (v == bk[KNN - 1] && gi < bi[KNN - 1])) {
      float cv = v; int ci = gi;
      #pragma unroll
      for (int q = 0; q < KNN; ++q) {
        bool take = (cv < bk[q]) || (cv == bk[q] && ci < bi[q]);
        if (take) {
          float tf = bk[q]; bk[q] = cv; cv = tf;
          int ti = bi[q]; bi[q] = ci; ci = ti;
        }
      }
    }
  }

  __shared__ float sk[512 * KNN];
  __shared__ int si[512 * KNN];
  __shared__ float wv_[8]; __shared__ int wi_[8];
  __shared__ int topIdx[KNN];
  #pragma unroll
  for (int q = 0; q < KNN; ++q) { sk[tid * KNN + q] = bk[q]; si[tid * KNN + q] = bi[q]; }
  __syncthreads();

  int p = 0;
  int lane = tid & 63, wv = tid >> 6;
  for (int rr = 0; rr < KNN; ++rr) {
    float myv = (p < KNN) ? sk[tid * KNN + p] : INF;
    int mygi = (p < KNN) ? si[tid * KNN + p] : 0x7fffffff;
    float hv = myv; int hgi = mygi;
    #pragma unroll
    for (int off = 32; off; off >>= 1) {
      float ov = __shfl_xor(hv, off); int oi = __shfl_xor(hgi, off);
      if (ov < hv || (ov == hv && oi < hgi)) { hv = ov; hgi = oi; }
    }
    if (lane == 0) { wv_[wv] = hv; wi_[wv] = hgi; }
    __syncthreads();
    float bv = wv_[0]; int bgi = wi_[0];
    #pragma unroll
    for (int w = 1; w < 8; ++w) {
      if (wv_[w] < bv || (wv_[w] == bv && wi_[w] < bgi)) { bv = wv_[w]; bgi = wi_[w]; }
    }
    if (p < KNN && myv == bv && mygi == bgi) p++;
    if (tid == 0) topIdx[rr] = bgi;
    __syncthreads();
  }

  // gather + dot: threads 0-255, thread == d
  if (tid < 256) {
    float cj = Cc[tid * NC + j];
    float acc = 0.f;
    #pragma unroll
    for (int k = 0; k < KNN; ++k) acc += X[(size_t)topIdx[k] * D + tid] * cj;
    acc = wave_sum(acc);
    __shared__ float rsum[4];
    if (lane == 0) rsum[wv] = acc;
    __syncthreads();
    if (tid == 0) dots[j] = (rsum[0] + rsum[1] + rsum[2] + rsum[3]) * (1.0f / KNN);
  }
}

// ============ final scalar: L_sparse_1 = mean(dots) ============
__global__ __launch_bounds__(64) void k_scal(const float* __restrict__ dots,
                                             float* __restrict__ out, int bs) {
  int lane = threadIdx.x;
  float v = (lane < NC) ? dots[lane] : 0.f;
  v = wave_sum(v);
  if (lane == 0) out[(size_t)2 * bs * NCLS] = v / (float)NC;
}

extern "C" void kernel_launch(void* const* d_in, const int* in_sizes, int n_in,
                              void* d_out, int out_size, void* d_ws, size_t ws_size,
                              hipStream_t stream) {
  const float* Xb = (const float*)d_in[0]; // train_embedding [bs][D]
  const float* XN = (const float*)d_in[1]; // train_embeddings [N][D]
  const float* C  = (const float*)d_in[2]; // concept [D][NC]
  const float* W  = (const float*)d_in[3]; // W_hx [D][NCLS]
  const float* bv = (const float*)d_in[4]; // b_hx [NCLS]
  float* out = (float*)d_out;

  int bs = in_sizes[0] / D;   // 4096
  int N  = in_sizes[1] / D;   // 200000
  int G  = (N + KROWS - 1) / KROWS;   // 1563

  float* w = (float*)d_ws;
  size_t offS    = 0;                         // 320 floats
  size_t offDots = 512;                       // 32 floats
  size_t offCK   = offDots + 64;              // NC*G*KNN floats
  size_t offCI   = offCK + (size_t)NC * G * KNN;

  float* S     = w + offS;
  float* dots  = w + offDots;
  float* candK = w + offCK;
  int*   candI = (int*)(w + offCI);

  k_key<<<dim3(G), dim3(512), 0, stream>>>(XN, C, candK, candI, N, G);
  k_gramsolve<<<dim3(1), dim3(1024), 0, stream>>>(C, W, S, out, bs);
  k_pred<<<dim3(bs / 8), dim3(256), 0, stream>>>(Xb, C, W, bv, S, out, bs);
  k_final<<<dim3(NC), dim3(512), 0, stream>>>(candK, candI, XN, C, dots, G);
  k_scal<<<dim3(1), dim3(64), 0, stream>>>(dots, out, bs);
}